// Round 14
// baseline (80.734 us; speedup 1.0000x reference)
//
#include <hip/hip_runtime.h>
#include <hip/hip_fp16.h>
#include <math.h>

#define CODEBOOK 4096
#define TPB 1024
#define NWAVES (TPB / 64)
#define CHUNKS 16
#define PTS_PER_BLOCK (TPB * CHUNKS)   // 16384
#define N_DENSE 7
#define N_HASH 9
#define PRIME_B2   0x1362u             // (PRIME mod 4096) << 1: byte-domain hash step

// LDS layout: hash tables at 0 (9 x 8192 B), bounce after. Dense tables now in GLOBAL.
#define BN_OFF 73728
#define SMEM_BYTES (73728 + 32768)     // 106,496

#define PIN2(a,b)           asm volatile("" : "+v"(a), "+v"(b))
#define PIN4(a,b,c,d)       asm volatile("" : "+v"(a), "+v"(b), "+v"(c), "+v"(d))
#define PIN8(a,b,c,d,e,f,g,i) \
    asm volatile("" : "+v"(a), "+v"(b), "+v"(c), "+v"(d), "+v"(e), "+v"(f), "+v"(g), "+v"(i))

#if defined(__has_builtin)
#if __has_builtin(__builtin_amdgcn_mfma_f32_16x16x16f16)
#define HAVE_MFMA16 1
#endif
#if __has_builtin(__builtin_elementwise_fma)
#define HAS_EFMA 1
#endif
#endif
#ifndef HAVE_MFMA16
#define HAVE_MFMA16 0
#endif

typedef _Float16 half4v  __attribute__((ext_vector_type(4)));
typedef float    float4v __attribute__((ext_vector_type(4)));
typedef float    f32x2   __attribute__((ext_vector_type(2)));

struct Params {
    int      res[16];
    float    rm1[16];
    int      q_off[N_DENSE];    // uint2-element offsets into gq (global), lods 0..6
    int      q_total;           // sum res^2 lods 0..6
};

__device__ __forceinline__ unsigned pack2(float a, float b) {
    return (unsigned)__half_as_ushort(__float2half(a))
         | ((unsigned)__half_as_ushort(__float2half(b)) << 16);
}
__device__ __forceinline__ float cvt_lo(unsigned u) {
    return __half2float(__ushort_as_half((unsigned short)(u & 0xffffu)));
}
__device__ __forceinline__ float cvt_hi(unsigned u) {
    return __half2float(__ushort_as_half((unsigned short)(u >> 16)));
}
// R = (A0,A1) + w*((B0,B1)-(A0,A1))  [v_pk ops]; return R.x + v*(R.y-R.x)
__device__ __forceinline__ float bilerp(float A0, float A1, float B0, float B1,
                                        float w, float v) {
    f32x2 A = {A0, A1}, B = {B0, B1}, W = {w, w};
#if defined(HAS_EFMA)
    f32x2 R = __builtin_elementwise_fma(W, B - A, A);
#else
    f32x2 R = {fmaf(w, B0 - A0, A0), fmaf(w, B1 - A1, A1)};
#endif
    return fmaf(v, R.y - R.x, R.x);
}

// ---- pre-kernel: decode dense LODs 0..6 once into global d_ws as clamp-baked
// corner quads (f00,f10 | f01,f11). Runs once per launch (~10501 threads). ----
__global__ void stage_quads(const float* __restrict__ latents,
                            const float* __restrict__ dec_w,
                            const float* __restrict__ dec_b,
                            uint2* __restrict__ gq, Params pr)
{
    const int t = blockIdx.x * blockDim.x + threadIdx.x;
    if (t >= pr.q_total) return;
    int l = 0;
    #pragma unroll
    for (int k = 1; k < N_DENSE; ++k) if (t >= pr.q_off[k]) l = k;
    const int e = t - pr.q_off[l];
    const int res = pr.res[l];
    const float dw = dec_w[0], db = dec_b[0];
    const int ix = e / res;
    const int iy = e - ix * res;
    const int ixp = min(ix + 1, res - 1);
    const int iyp = min(iy + 1, res - 1);
    const float* lat = latents + l * CODEBOOK;
    const float* r0 = lat + ix * res;
    const float* r1 = lat + ixp * res;
    uint2 qv;
    qv.x = pack2(fmaf(r0[iy],  dw, db), fmaf(r1[iy],  dw, db));
    qv.y = pack2(fmaf(r0[iyp], dw, db), fmaf(r1[iyp], dw, db));
    gq[t] = qv;
}

__global__ __launch_bounds__(TPB, 4) void shacira_fwd(
    const float* __restrict__ x,
    const float* __restrict__ latents,
    const float* __restrict__ dec_w,
    const float* __restrict__ dec_b,
    const float* __restrict__ w1,
    const float* __restrict__ b1,
    const float* __restrict__ w2,
    const float* __restrict__ b2,
    float* __restrict__ out,
    const uint2* __restrict__ gq,
    Params pr)
{
    __shared__ __align__(16) unsigned char smem[SMEM_BYTES];
    unsigned short* hl = (unsigned short*)smem;              // 9 x 4096 f16 bit patterns
#if HAVE_MFMA16
    unsigned*   bounce = (unsigned*)(smem + BN_OFF);
#endif

    const int tid = threadIdx.x;
    const float dw = dec_w[0];
    const float db = dec_b[0];

    // ---- stage hashed LODs 7..15 as f16 bit patterns (dense now global) ----
    #pragma unroll
    for (int l = 0; l < N_HASH; ++l) {
        const float* lat = latents + (N_DENSE + l) * CODEBOOK;
        for (int e = tid; e < CODEBOOK; e += TPB)
            hl[l * CODEBOOK + e] = __half_as_ushort(__float2half(fmaf(lat[e], dw, db)));
    }
    __syncthreads();

    const int lane = tid & 63;
    const int wid  = tid >> 6;
    const int q    = lane >> 4;
    const int r15  = lane & 15;
    const char* hp  = (const char*)smem;          // hash base (offset 0)
    const char* hp8 = (const char*)smem + 65536;  // 9th hash table (lod 15)

#if HAVE_MFMA16
    // ---- one-time MFMA fragments: A=W^T, C=bias (broadcast over point-cols) ----
    half4v a1f, a2f;
    float4v c1f, c2f;
    #pragma unroll
    for (int j = 0; j < 4; ++j) {
        const int k = q * 4 + j;
        a1f[j] = (_Float16)w1[k * 16 + r15];
        a2f[j] = (r15 < 3) ? (_Float16)w2[k * 3 + r15] : (_Float16)0.f;
        c1f[j] = b1[k];
        c2f[j] = b2[min(k, 2)];
    }
    const int sW = (lane >> 2) & 1;         // write-side XOR swizzle bit
    const int sR = (r15 >> 2) & 1;          // read-side  XOR swizzle bit
    unsigned* wbase = &bounce[wid * 512 + lane * 8];
#endif

    const int pbase0 = blockIdx.x * PTS_PER_BLOCK;
    const float2* xp = reinterpret_cast<const float2*>(x) + pbase0;
    float* outp = out + (size_t)pbase0 * 3;

    float2 xy = xp[tid];                      // chunk-0 coords

    for (int c = 0; c < CHUNKS; ++c) {
        const int t64 = c * TPB + (tid & ~63);   // wave's first point (block-local)

        // ====== Issue DENSE global gathers first (63-deep vmcnt window; L1/L2-hot
        // 84 KB table). Their latency hides under the hash LDS math below. ======
        float fxs[8], fys[8];
        uint2 qvv[N_DENSE];
        #pragma unroll
        for (int l = 0; l < N_DENSE; ++l) {
            const int res = pr.res[l];
            f32x2 pxy = (f32x2){xy.x, xy.y} * (f32x2){pr.rm1[l], pr.rm1[l]};
            int i0x = (int)pxy.x, i0y = (int)pxy.y;  // trunc == floor (>=0); clamps dead (r8)
            fxs[l] = __builtin_amdgcn_fractf(pxy.x);
            fys[l] = __builtin_amdgcn_fractf(pxy.y);
            qvv[l] = gq[pr.q_off[l] + (int)__umul24((unsigned)i0x, (unsigned)res) + i0y];
        }

        // ====== Issue all hash LDS gathers (byte-domain indexing, r9-r11) ======
        unsigned h7[4];
        {
            f32x2 pxy = (f32x2){xy.x, xy.y} * (f32x2){pr.rm1[7], pr.rm1[7]};
            int i0x = (int)pxy.x, i0y = (int)pxy.y;
            fxs[7] = __builtin_amdgcn_fractf(pxy.x);
            fys[7] = __builtin_amdgcn_fractf(pxy.y);
            unsigned ux0b = (unsigned)(i0x << 1), ux1b = ux0b + 2u;
            unsigned hyb0 = __umul24((unsigned)i0y, PRIME_B2);
            unsigned hyb1 = hyb0 + PRIME_B2;
            h7[0] = (unsigned)*(const unsigned short*)(hp + ((ux0b ^ hyb0) & 0x1FFEu));
            h7[1] = (unsigned)*(const unsigned short*)(hp + ((ux1b ^ hyb0) & 0x1FFEu));
            h7[2] = (unsigned)*(const unsigned short*)(hp + ((ux0b ^ hyb1) & 0x1FFEu));
            h7[3] = (unsigned)*(const unsigned short*)(hp + ((ux1b ^ hyb1) & 0x1FFEu));
        }
        unsigned hv[8][4];
        #pragma unroll
        for (int i = 0; i < 8; ++i) {            // lods 8..15 = hash tables 1..8
            const int l = 8 + i;
            f32x2 pxy = (f32x2){xy.x, xy.y} * (f32x2){pr.rm1[l], pr.rm1[l]};
            int i0x = (int)pxy.x, i0y = (int)pxy.y;
            unsigned ux0b = (unsigned)(i0x << 1), ux1b = ux0b + 2u;
            unsigned hyb0 = __umul24((unsigned)i0y, PRIME_B2);
            unsigned hyb1 = hyb0 + PRIME_B2;
            if (i < 7) {   // base 8192*(i+1) <= 57344: folds into ds offset imm
                const char* tb = hp + 8192 * (i + 1);
                hv[i][0] = (unsigned)*(const unsigned short*)(tb + ((ux0b ^ hyb0) & 0x1FFEu));
                hv[i][1] = (unsigned)*(const unsigned short*)(tb + ((ux1b ^ hyb0) & 0x1FFEu));
                hv[i][2] = (unsigned)*(const unsigned short*)(tb + ((ux0b ^ hyb1) & 0x1FFEu));
                hv[i][3] = (unsigned)*(const unsigned short*)(tb + ((ux1b ^ hyb1) & 0x1FFEu));
            } else {       // lod 15: base 65536 via pointer
                hv[i][0] = (unsigned)*(const unsigned short*)(hp8 + ((ux0b ^ hyb0) & 0x1FFEu));
                hv[i][1] = (unsigned)*(const unsigned short*)(hp8 + ((ux1b ^ hyb0) & 0x1FFEu));
                hv[i][2] = (unsigned)*(const unsigned short*)(hp8 + ((ux0b ^ hyb1) & 0x1FFEu));
                hv[i][3] = (unsigned)*(const unsigned short*)(hp8 + ((ux1b ^ hyb1) & 0x1FFEu));
            }
        }

        // prefetch next chunk's coords
        const int cn = (c + 1 < CHUNKS) ? (c + 1) : c;
        float2 xy_next = xp[cn * TPB + tid];

        float h[16];

        // ---- HASH math first (grouped partial lgkm waits, r13 structure);
        //      dense global loads remain in flight underneath ----
        PIN8(h7[0], h7[1], h7[2], h7[3], hv[0][0], hv[0][1], hv[0][2], hv[0][3]);
        PIN8(hv[1][0], hv[1][1], hv[1][2], hv[1][3], hv[2][0], hv[2][1], hv[2][2], hv[2][3]);
        h[7] = bilerp(cvt_lo(h7[0]), cvt_lo(h7[1]), cvt_lo(h7[2]), cvt_lo(h7[3]),
                      fys[7], fxs[7]);
        #pragma unroll
        for (int i = 0; i < 3; ++i) {
            const int l = 8 + i;
            f32x2 pxy = (f32x2){xy.x, xy.y} * (f32x2){pr.rm1[l], pr.rm1[l]};
            float fx = __builtin_amdgcn_fractf(pxy.x);
            float fy = __builtin_amdgcn_fractf(pxy.y);
            h[l] = bilerp(cvt_lo(hv[i][0]), cvt_lo(hv[i][1]),
                          cvt_lo(hv[i][2]), cvt_lo(hv[i][3]), fy, fx);
        }
        PIN8(hv[3][0], hv[3][1], hv[3][2], hv[3][3], hv[4][0], hv[4][1], hv[4][2], hv[4][3]);
        #pragma unroll
        for (int i = 3; i < 5; ++i) {
            const int l = 8 + i;
            f32x2 pxy = (f32x2){xy.x, xy.y} * (f32x2){pr.rm1[l], pr.rm1[l]};
            float fx = __builtin_amdgcn_fractf(pxy.x);
            float fy = __builtin_amdgcn_fractf(pxy.y);
            h[l] = bilerp(cvt_lo(hv[i][0]), cvt_lo(hv[i][1]),
                          cvt_lo(hv[i][2]), cvt_lo(hv[i][3]), fy, fx);
        }
        PIN8(hv[5][0], hv[5][1], hv[5][2], hv[5][3], hv[6][0], hv[6][1], hv[6][2], hv[6][3]);
        PIN4(hv[7][0], hv[7][1], hv[7][2], hv[7][3]);
        #pragma unroll
        for (int i = 5; i < 8; ++i) {
            const int l = 8 + i;
            f32x2 pxy = (f32x2){xy.x, xy.y} * (f32x2){pr.rm1[l], pr.rm1[l]};
            float fx = __builtin_amdgcn_fractf(pxy.x);
            float fy = __builtin_amdgcn_fractf(pxy.y);
            h[l] = bilerp(cvt_lo(hv[i][0]), cvt_lo(hv[i][1]),
                          cvt_lo(hv[i][2]), cvt_lo(hv[i][3]), fy, fx);
        }

        // ---- DENSE math last: vmcnt wait lands here, after all hash math ----
        PIN8(qvv[0].x, qvv[0].y, qvv[1].x, qvv[1].y, qvv[2].x, qvv[2].y, qvv[3].x, qvv[3].y);
        PIN8(qvv[4].x, qvv[4].y, qvv[5].x, qvv[5].y, qvv[6].x, qvv[6].y, h7[0], h7[1]);
        #pragma unroll
        for (int l = 0; l < N_DENSE; ++l) {
            // qv.x=(f00,f10) y0-row, qv.y=(f01,f11) y1-row: x-lerp pair, then y
            h[l] = bilerp(cvt_lo(qvv[l].x), cvt_lo(qvv[l].y),
                          cvt_hi(qvv[l].x), cvt_hi(qvv[l].y), fxs[l], fys[l]);
        }

#if HAVE_MFMA16
        // ---- pack h to f16 and transpose via wave-private LDS bounce ----
        unsigned hw[8];
        #pragma unroll
        for (int i = 0; i < 8; ++i)
            hw[i] = __builtin_bit_cast(unsigned,
                        __builtin_amdgcn_cvt_pkrtz(h[2 * i], h[2 * i + 1]));
        *reinterpret_cast<uint4*>(wbase + sW * 4)       = uint4{hw[0], hw[1], hw[2], hw[3]};
        *reinterpret_cast<uint4*>(wbase + (sW ^ 1) * 4) = uint4{hw[4], hw[5], hw[6], hw[7]};

        // ---- 4 tiles x (MFMA L1 -> relu/pack -> MFMA L2 -> coalesced store) ----
        #pragma unroll
        for (int t = 0; t < 4; ++t) {
            const int row = 16 * t + r15;
            const unsigned* rb = &bounce[wid * 512 + row * 8 + ((q * 2) ^ (sR * 4))];
            half4v bf = *reinterpret_cast<const half4v*>(rb);
            float4v d1 = __builtin_amdgcn_mfma_f32_16x16x16f16(a1f, bf, c1f, 0, 0, 0);
            unsigned u0 = __builtin_bit_cast(unsigned,
                              __builtin_amdgcn_cvt_pkrtz(fmaxf(d1[0], 0.f), fmaxf(d1[1], 0.f)));
            unsigned u1 = __builtin_bit_cast(unsigned,
                              __builtin_amdgcn_cvt_pkrtz(fmaxf(d1[2], 0.f), fmaxf(d1[3], 0.f)));
            uint2 uu; uu.x = u0; uu.y = u1;
            half4v rp = __builtin_bit_cast(half4v, uu);
            float4v d2 = __builtin_amdgcn_mfma_f32_16x16x16f16(a2f, rp, c2f, 0, 0, 0);
            if (lane < 16) {     // lanes 0-15 hold out rows 0-2 of point (16t + r15)
                float* op = outp + (size_t)(t64 + 16 * t + r15) * 3;
                op[0] = d2[0]; op[1] = d2[1]; op[2] = d2[2];
            }
        }
#else
        // ---- fallback: scalar f32 MLP ----
        float o0 = b2[0], o1 = b2[1], o2 = b2[2];
        #pragma unroll
        for (int k = 0; k < 16; ++k) {
            float acc = b1[k];
            #pragma unroll
            for (int l = 0; l < 16; ++l)
                acc = fmaf(h[l], w1[l * 16 + k], acc);
            acc = fmaxf(acc, 0.f);
            o0 = fmaf(acc, w2[k * 3 + 0], o0);
            o1 = fmaf(acc, w2[k * 3 + 1], o1);
            o2 = fmaf(acc, w2[k * 3 + 2], o2);
        }
        float* op = outp + (size_t)(t64 + lane) * 3;
        op[0] = o0; op[1] = o1; op[2] = o2;
#endif
        xy = xy_next;
    }
}

extern "C" void kernel_launch(void* const* d_in, const int* in_sizes, int n_in,
                              void* d_out, int out_size, void* d_ws, size_t ws_size,
                              hipStream_t stream)
{
    // RES exactly as the Python reference (float64 pow + floor) — verified rounds 1-13.
    Params pr;
    const double growth = pow(512.0 / 16.0, 1.0 / 15.0);
    for (int l = 0; l < 16; ++l) {
        pr.res[l] = (int)floor(16.0 * pow(growth, (double)l));
        pr.rm1[l] = (float)(pr.res[l] - 1);
    }
    int qoff = 0;
    for (int l = 0; l < N_DENSE; ++l) {
        pr.q_off[l] = qoff;
        qoff += pr.res[l] * pr.res[l];
    }
    pr.q_total = qoff;                                   // ~10501 cells, 84 KB in d_ws

    const int n = in_sizes[0] / 2;                       // 4194304 (divides 16384 exactly)
    const int blocks = n / PTS_PER_BLOCK;                // 256

    uint2* gq = (uint2*)d_ws;

    stage_quads<<<(pr.q_total + 255) / 256, 256, 0, stream>>>(
        (const float*)d_in[1], (const float*)d_in[2], (const float*)d_in[3], gq, pr);

    shacira_fwd<<<blocks, TPB, 0, stream>>>(
        (const float*)d_in[0], (const float*)d_in[1], (const float*)d_in[2],
        (const float*)d_in[3], (const float*)d_in[4], (const float*)d_in[5],
        (const float*)d_in[6], (const float*)d_in[7], (float*)d_out, gq, pr);
}

// Round 15
// 72.306 us; speedup vs baseline: 1.1166x; 1.1166x over previous
//
#include <hip/hip_runtime.h>
#include <hip/hip_fp16.h>
#include <math.h>

#define CODEBOOK 4096
#define TPB 1024
#define NWAVES (TPB / 64)
#define CHUNKS 16
#define PTS_PER_BLOCK (TPB * CHUNKS)   // 16384
#define N_QUAD 4
#define N_PAIR 3
#define N_DENSE 7
#define N_HASH 9
#define QMAX 2305                      // sum res^2, lods 0..3 (exact: 256+400+625+1024)
#define PMAX 8196                      // sum res^2, lods 4..6 (exact: 1600+2500+4096)
#define PRIME_B2   0x1362u             // (PRIME mod 4096) << 1: byte-domain hash step

// LDS layout (manual, hash tables FIRST so 8/9 bases fold into ds offset imm):
#define HL_OFF 0
#define DQ_OFF 73728
#define DP_OFF 92168
#define BN_OFF 124960
#define SMEM_BYTES 157728

// REVERT to round-13 state (best: 72.36 us). Round-14's dense->global A/B
// regressed (80.7 us): vmem divergent-gather cost > LDS gather cost, even
// though LDS bank conflicts dropped 1.54e7 -> 1.22e7. LDS is the cheapest
// gather machine for this pattern; the additive VALU+LDS wall is structural.
#define PIN2(a,b)           asm volatile("" : "+v"(a), "+v"(b))
#define PIN8(a,b,c,d,e,f,g,i) \
    asm volatile("" : "+v"(a), "+v"(b), "+v"(c), "+v"(d), "+v"(e), "+v"(f), "+v"(g), "+v"(i))

#if defined(__has_builtin)
#if __has_builtin(__builtin_amdgcn_mfma_f32_16x16x16f16)
#define HAVE_MFMA16 1
#endif
#if __has_builtin(__builtin_elementwise_fma)
#define HAS_EFMA 1
#endif
#endif
#ifndef HAVE_MFMA16
#define HAVE_MFMA16 0
#endif

typedef _Float16 half4v  __attribute__((ext_vector_type(4)));
typedef float    float4v __attribute__((ext_vector_type(4)));
typedef float    f32x2   __attribute__((ext_vector_type(2)));

struct Params {
    int      res[16];
    float    rm1[16];
    int      q_off[N_QUAD];     // uint2-element offsets into dq
    unsigned magic[N_QUAD];     // staging: ix = (e*magic)>>shift == e/res
    int      shift[N_QUAD];
    int      p_off[N_PAIR];     // u32-element offsets into dp (lods 4..6)
};

__device__ __forceinline__ unsigned pack2(float a, float b) {
    return (unsigned)__half_as_ushort(__float2half(a))
         | ((unsigned)__half_as_ushort(__float2half(b)) << 16);
}
__device__ __forceinline__ float cvt_lo(unsigned u) {
    return __half2float(__ushort_as_half((unsigned short)(u & 0xffffu)));
}
__device__ __forceinline__ float cvt_hi(unsigned u) {
    return __half2float(__ushort_as_half((unsigned short)(u >> 16)));
}
// R = (A0,A1) + w*((B0,B1)-(A0,A1))  [v_pk ops]; return R.x + v*(R.y-R.x)
__device__ __forceinline__ float bilerp(float A0, float A1, float B0, float B1,
                                        float w, float v) {
    f32x2 A = {A0, A1}, B = {B0, B1}, W = {w, w};
#if defined(HAS_EFMA)
    f32x2 R = __builtin_elementwise_fma(W, B - A, A);
#else
    f32x2 R = {fmaf(w, B0 - A0, A0), fmaf(w, B1 - A1, A1)};
#endif
    return fmaf(v, R.y - R.x, R.x);
}

__global__ __launch_bounds__(TPB, 4) void shacira_fwd(
    const float* __restrict__ x,
    const float* __restrict__ latents,
    const float* __restrict__ dec_w,
    const float* __restrict__ dec_b,
    const float* __restrict__ w1,
    const float* __restrict__ b1,
    const float* __restrict__ w2,
    const float* __restrict__ b2,
    float* __restrict__ out,
    Params pr)
{
    __shared__ __align__(16) unsigned char smem[SMEM_BYTES];
    unsigned short* hl = (unsigned short*)(smem + HL_OFF);   // 9 x 4096 f16 (bit patterns)
    uint2*          dq = (uint2*)(smem + DQ_OFF);
    unsigned*       dp = (unsigned*)(smem + DP_OFF);
#if HAVE_MFMA16
    unsigned*   bounce = (unsigned*)(smem + BN_OFF);
#endif

    const int tid = threadIdx.x;
    const float dw = dec_w[0];
    const float db = dec_b[0];

    // ---- stage quad LODs 0..3: clamp-baked corner quads (f00,f10 | f01,f11) ----
    #pragma unroll
    for (int l = 0; l < N_QUAD; ++l) {
        const int res = pr.res[l];
        const int n = res * res;
        const unsigned M = pr.magic[l];
        const int sh = pr.shift[l];
        const int off = pr.q_off[l];
        const float* lat = latents + l * CODEBOOK;
        for (int e = tid; e < n; e += TPB) {
            int ix = (int)(((unsigned)e * M) >> sh);    // e / res (host-verified)
            int iy = e - ix * res;
            int ixp = min(ix + 1, res - 1);
            int iyp = min(iy + 1, res - 1);
            const float* r0 = lat + ix * res;
            const float* r1 = lat + ixp * res;
            uint2 qv;
            qv.x = pack2(fmaf(r0[iy],  dw, db), fmaf(r1[iy],  dw, db));
            qv.y = pack2(fmaf(r0[iyp], dw, db), fmaf(r1[iyp], dw, db));
            dq[off + e] = qv;
        }
    }
    // ---- stage pair LODs 4..6: (f[e], f[e+1]) y-pairs ----
    #pragma unroll
    for (int l = 0; l < N_PAIR; ++l) {
        const int res = pr.res[4 + l];
        const int n = res * res;
        const int off = pr.p_off[l];
        const float* lat = latents + (4 + l) * CODEBOOK;
        for (int e = tid; e < n; e += TPB) {
            float a = fmaf(lat[e],     dw, db);
            float b = fmaf(lat[e + 1], dw, db);  // e+1 at row end: weight fy==0 (finite garbage ok)
            dp[off + e] = pack2(a, b);
        }
    }
    // ---- stage hashed LODs 7..15 as f16 BIT PATTERNS ----
    #pragma unroll
    for (int l = 0; l < N_HASH; ++l) {
        const float* lat = latents + (N_DENSE + l) * CODEBOOK;
        for (int e = tid; e < CODEBOOK; e += TPB)
            hl[l * CODEBOOK + e] = __half_as_ushort(__float2half(fmaf(lat[e], dw, db)));
    }
    __syncthreads();

    const int lane = tid & 63;
    const int wid  = tid >> 6;
    const int q    = lane >> 4;
    const int r15  = lane & 15;
    const char* hp  = (const char*)smem;          // hash base (offset 0)
    const char* hp8 = (const char*)smem + 65536;  // 9th hash table (lod 15)

#if HAVE_MFMA16
    // ---- one-time MFMA fragments: A=W^T, C=bias (broadcast over point-cols) ----
    half4v a1f, a2f;
    float4v c1f, c2f;
    #pragma unroll
    for (int j = 0; j < 4; ++j) {
        const int k = q * 4 + j;
        a1f[j] = (_Float16)w1[k * 16 + r15];
        a2f[j] = (r15 < 3) ? (_Float16)w2[k * 3 + r15] : (_Float16)0.f;
        c1f[j] = b1[k];
        c2f[j] = b2[min(k, 2)];
    }
    const int sW = (lane >> 2) & 1;         // write-side XOR swizzle bit
    const int sR = (r15 >> 2) & 1;          // read-side  XOR swizzle bit
    unsigned* wbase = &bounce[wid * 512 + lane * 8];
#endif

    const int pbase0 = blockIdx.x * PTS_PER_BLOCK;
    const float2* xp = reinterpret_cast<const float2*>(x) + pbase0;
    float* outp = out + (size_t)pbase0 * 3;

    float2 xy = xp[tid];                      // chunk-0 coords

    for (int c = 0; c < CHUNKS; ++c) {
        const int t64 = c * TPB + (tid & ~63);   // wave's first point (block-local)

        // ============ Issue ALL gathers in group order (G0..G3) ============
        float fxs[8], fys[8];
        uint2 qvv[N_QUAD];
        unsigned pu0[N_PAIR], pu1[N_PAIR];
        unsigned h7[4];
        #pragma unroll
        for (int l = 0; l < 8; ++l) {
            const int res = pr.res[l];
            f32x2 pxy = (f32x2){xy.x, xy.y} * (f32x2){pr.rm1[l], pr.rm1[l]};
            int i0x = (int)pxy.x, i0y = (int)pxy.y;  // trunc == floor (>=0)
            fxs[l] = __builtin_amdgcn_fractf(pxy.x);
            fys[l] = __builtin_amdgcn_fractf(pxy.y);
            if (l < N_QUAD) {
                qvv[l] = dq[pr.q_off[l] + (int)__umul24((unsigned)i0x, (unsigned)res) + i0y];
            } else if (l < N_DENSE) {
                int e = pr.p_off[l - 4] + (int)__umul24((unsigned)i0x, (unsigned)res) + i0y;
                pu0[l - 4] = dp[e];
                pu1[l - 4] = dp[e + res];
            } else {  // l == 7: hash table 0 (base 0, imm-folds)
                unsigned ux0b = (unsigned)(i0x << 1), ux1b = ux0b + 2u;
                unsigned hyb0 = __umul24((unsigned)i0y, PRIME_B2);
                unsigned hyb1 = hyb0 + PRIME_B2;
                h7[0] = (unsigned)*(const unsigned short*)(hp + ((ux0b ^ hyb0) & 0x1FFEu));
                h7[1] = (unsigned)*(const unsigned short*)(hp + ((ux1b ^ hyb0) & 0x1FFEu));
                h7[2] = (unsigned)*(const unsigned short*)(hp + ((ux0b ^ hyb1) & 0x1FFEu));
                h7[3] = (unsigned)*(const unsigned short*)(hp + ((ux1b ^ hyb1) & 0x1FFEu));
            }
        }
        unsigned hv[8][4];
        #pragma unroll
        for (int i = 0; i < 8; ++i) {            // lods 8..15 = hash tables 1..8
            const int l = 8 + i;
            f32x2 pxy = (f32x2){xy.x, xy.y} * (f32x2){pr.rm1[l], pr.rm1[l]};
            int i0x = (int)pxy.x, i0y = (int)pxy.y;
            unsigned ux0b = (unsigned)(i0x << 1), ux1b = ux0b + 2u;
            unsigned hyb0 = __umul24((unsigned)i0y, PRIME_B2);
            unsigned hyb1 = hyb0 + PRIME_B2;
            if (i < 7) {   // base 8192*(i+1) <= 57344: folds into ds offset imm
                const char* tb = hp + 8192 * (i + 1);
                hv[i][0] = (unsigned)*(const unsigned short*)(tb + ((ux0b ^ hyb0) & 0x1FFEu));
                hv[i][1] = (unsigned)*(const unsigned short*)(tb + ((ux1b ^ hyb0) & 0x1FFEu));
                hv[i][2] = (unsigned)*(const unsigned short*)(tb + ((ux0b ^ hyb1) & 0x1FFEu));
                hv[i][3] = (unsigned)*(const unsigned short*)(tb + ((ux1b ^ hyb1) & 0x1FFEu));
            } else {       // lod 15: base 65536 via pointer
                hv[i][0] = (unsigned)*(const unsigned short*)(hp8 + ((ux0b ^ hyb0) & 0x1FFEu));
                hv[i][1] = (unsigned)*(const unsigned short*)(hp8 + ((ux1b ^ hyb0) & 0x1FFEu));
                hv[i][2] = (unsigned)*(const unsigned short*)(hp8 + ((ux0b ^ hyb1) & 0x1FFEu));
                hv[i][3] = (unsigned)*(const unsigned short*)(hp8 + ((ux1b ^ hyb1) & 0x1FFEu));
            }
        }

        // prefetch next chunk's coords: global latency hides under the math phase
        const int cn = (c + 1 < CHUNKS) ? (c + 1) : c;
        float2 xy_next = xp[cn * TPB + tid];

        float h[16];

        // ---- G0: pin quads, lerp h0-3 (later groups' loads still in flight) ----
        PIN8(qvv[0].x, qvv[0].y, qvv[1].x, qvv[1].y, qvv[2].x, qvv[2].y, qvv[3].x, qvv[3].y);
        #pragma unroll
        for (int l = 0; l < N_QUAD; ++l) {
            h[l] = bilerp(cvt_lo(qvv[l].x), cvt_lo(qvv[l].y),
                          cvt_hi(qvv[l].x), cvt_hi(qvv[l].y), fxs[l], fys[l]);
        }

        // ---- G1: pin pairs + lod7, lerp h4-7 ----
        PIN8(pu0[0], pu0[1], pu0[2], pu1[0], pu1[1], pu1[2], h7[0], h7[1]);
        PIN2(h7[2], h7[3]);
        #pragma unroll
        for (int l = N_QUAD; l < N_DENSE; ++l) {
            h[l] = bilerp(cvt_lo(pu0[l - 4]), cvt_lo(pu1[l - 4]),
                          cvt_hi(pu0[l - 4]), cvt_hi(pu1[l - 4]), fys[l], fxs[l]);
        }
        h[7] = bilerp(cvt_lo(h7[0]), cvt_lo(h7[1]), cvt_lo(h7[2]), cvt_lo(h7[3]),
                      fys[7], fxs[7]);

        // ---- G2: pin hv0-3, lerp h8-11 ----
        PIN8(hv[0][0], hv[0][1], hv[0][2], hv[0][3], hv[1][0], hv[1][1], hv[1][2], hv[1][3]);
        PIN8(hv[2][0], hv[2][1], hv[2][2], hv[2][3], hv[3][0], hv[3][1], hv[3][2], hv[3][3]);
        #pragma unroll
        for (int i = 0; i < 4; ++i) {
            const int l = 8 + i;
            f32x2 pxy = (f32x2){xy.x, xy.y} * (f32x2){pr.rm1[l], pr.rm1[l]};
            float fx = __builtin_amdgcn_fractf(pxy.x);
            float fy = __builtin_amdgcn_fractf(pxy.y);
            h[l] = bilerp(cvt_lo(hv[i][0]), cvt_lo(hv[i][1]),
                          cvt_lo(hv[i][2]), cvt_lo(hv[i][3]), fy, fx);
        }

        // ---- G3: pin hv4-7, lerp h12-15 ----
        PIN8(hv[4][0], hv[4][1], hv[4][2], hv[4][3], hv[5][0], hv[5][1], hv[5][2], hv[5][3]);
        PIN8(hv[6][0], hv[6][1], hv[6][2], hv[6][3], hv[7][0], hv[7][1], hv[7][2], hv[7][3]);
        #pragma unroll
        for (int i = 4; i < 8; ++i) {
            const int l = 8 + i;
            f32x2 pxy = (f32x2){xy.x, xy.y} * (f32x2){pr.rm1[l], pr.rm1[l]};
            float fx = __builtin_amdgcn_fractf(pxy.x);
            float fy = __builtin_amdgcn_fractf(pxy.y);
            h[l] = bilerp(cvt_lo(hv[i][0]), cvt_lo(hv[i][1]),
                          cvt_lo(hv[i][2]), cvt_lo(hv[i][3]), fy, fx);
        }

#if HAVE_MFMA16
        // ---- pack h to f16 and transpose via wave-private LDS bounce ----
        unsigned hw[8];
        #pragma unroll
        for (int i = 0; i < 8; ++i)
            hw[i] = __builtin_bit_cast(unsigned,
                        __builtin_amdgcn_cvt_pkrtz(h[2 * i], h[2 * i + 1]));
        *reinterpret_cast<uint4*>(wbase + sW * 4)       = uint4{hw[0], hw[1], hw[2], hw[3]};
        *reinterpret_cast<uint4*>(wbase + (sW ^ 1) * 4) = uint4{hw[4], hw[5], hw[6], hw[7]};

        // ---- 4 tiles x (MFMA L1 -> relu/pack -> MFMA L2 -> coalesced store) ----
        #pragma unroll
        for (int t = 0; t < 4; ++t) {
            const int row = 16 * t + r15;
            const unsigned* rb = &bounce[wid * 512 + row * 8 + ((q * 2) ^ (sR * 4))];
            half4v bf = *reinterpret_cast<const half4v*>(rb);
            float4v d1 = __builtin_amdgcn_mfma_f32_16x16x16f16(a1f, bf, c1f, 0, 0, 0);
            unsigned u0 = __builtin_bit_cast(unsigned,
                              __builtin_amdgcn_cvt_pkrtz(fmaxf(d1[0], 0.f), fmaxf(d1[1], 0.f)));
            unsigned u1 = __builtin_bit_cast(unsigned,
                              __builtin_amdgcn_cvt_pkrtz(fmaxf(d1[2], 0.f), fmaxf(d1[3], 0.f)));
            uint2 uu; uu.x = u0; uu.y = u1;
            half4v rp = __builtin_bit_cast(half4v, uu);
            float4v d2 = __builtin_amdgcn_mfma_f32_16x16x16f16(a2f, rp, c2f, 0, 0, 0);
            if (lane < 16) {     // lanes 0-15 hold out rows 0-2 of point (16t + r15)
                float* op = outp + (size_t)(t64 + 16 * t + r15) * 3;
                op[0] = d2[0]; op[1] = d2[1]; op[2] = d2[2];
            }
        }
#else
        // ---- fallback: scalar f32 MLP ----
        float o0 = b2[0], o1 = b2[1], o2 = b2[2];
        #pragma unroll
        for (int k = 0; k < 16; ++k) {
            float acc = b1[k];
            #pragma unroll
            for (int l = 0; l < 16; ++l)
                acc = fmaf(h[l], w1[l * 16 + k], acc);
            acc = fmaxf(acc, 0.f);
            o0 = fmaf(acc, w2[k * 3 + 0], o0);
            o1 = fmaf(acc, w2[k * 3 + 1], o1);
            o2 = fmaf(acc, w2[k * 3 + 2], o2);
        }
        float* op = outp + (size_t)(t64 + lane) * 3;
        op[0] = o0; op[1] = o1; op[2] = o2;
#endif
        xy = xy_next;
    }
}

extern "C" void kernel_launch(void* const* d_in, const int* in_sizes, int n_in,
                              void* d_out, int out_size, void* d_ws, size_t ws_size,
                              hipStream_t stream)
{
    // RES exactly as the Python reference (float64 pow + floor) — verified rounds 1-14.
    Params pr;
    const double growth = pow(512.0 / 16.0, 1.0 / 15.0);
    for (int l = 0; l < 16; ++l) {
        pr.res[l] = (int)floor(16.0 * pow(growth, (double)l));
        pr.rm1[l] = (float)(pr.res[l] - 1);
    }
    int qoff = 0;
    for (int l = 0; l < N_QUAD; ++l) {
        pr.q_off[l] = qoff;
        qoff += pr.res[l] * pr.res[l];
        const int d = pr.res[l];
        pr.magic[l] = 0; pr.shift[l] = 0;
        for (int s = 12; s <= 23; ++s) {
            unsigned long long M = ((1ull << s) + d - 1) / d;
            if ((unsigned long long)(d * d - 1) * M >= (1ull << 32)) continue;
            bool ok = true;
            for (int e = 0; e < d * d; ++e)
                if ((int)(((unsigned long long)e * M) >> s) != e / d) { ok = false; break; }
            if (ok) { pr.magic[l] = (unsigned)M; pr.shift[l] = s; break; }
        }
    }
    int poff = 0;
    for (int l = 0; l < N_PAIR; ++l) {
        pr.p_off[l] = poff;
        poff += pr.res[4 + l] * pr.res[4 + l];
    }

    const int n = in_sizes[0] / 2;                       // 4194304 (divides 16384 exactly)
    const int blocks = n / PTS_PER_BLOCK;                // 256

    shacira_fwd<<<blocks, TPB, 0, stream>>>(
        (const float*)d_in[0], (const float*)d_in[1], (const float*)d_in[2],
        (const float*)d_in[3], (const float*)d_in[4], (const float*)d_in[5],
        (const float*)d_in[6], (const float*)d_in[7], (float*)d_out, pr);
}

// Round 16
// 71.264 us; speedup vs baseline: 1.1329x; 1.0146x over previous
//
#include <hip/hip_runtime.h>
#include <hip/hip_fp16.h>
#include <math.h>

#define CODEBOOK 4096
#define TPB 1024
#define NWAVES (TPB / 64)
#define CHUNKS 16
#define PTS_PER_BLOCK (TPB * CHUNKS)   // 16384
#define N_QUAD 4
#define N_PAIR 3
#define N_DENSE 7
#define N_HASH 9
#define QMAX 2305                      // sum res^2, lods 0..3
#define PMAX 8196                      // sum res^2, lods 4..6
#define PRIME_B2   0x1362u             // (PRIME mod 4096) << 1: byte-domain hash step

#define HL_OFF 0
#define DQ_OFF 73728
#define DP_OFF 92168
#define BN_OFF 124960
#define SMEM_BYTES 157728

// Modulo-schedule pins. Volatile asms execute in PROGRAM ORDER relative to each
// other; pinning (a) each issue-group's values right after issue and (b) each
// math result right after computing it freezes the alternating issue/math
// schedule. r13 pinned only loads -> math sank to the end -> the 15-deep
// lgkmcnt issue-stall serialized load phase vs math phase (additive wall).
#define PIN1(a)             asm volatile("" : "+v"(a))
#define PIN2(a,b)           asm volatile("" : "+v"(a), "+v"(b))
#define PIN3(a,b,c)         asm volatile("" : "+v"(a), "+v"(b), "+v"(c))
#define PIN4(a,b,c,d)       asm volatile("" : "+v"(a), "+v"(b), "+v"(c), "+v"(d))
#define PIN8(a,b,c,d,e,f,g,i) \
    asm volatile("" : "+v"(a), "+v"(b), "+v"(c), "+v"(d), "+v"(e), "+v"(f), "+v"(g), "+v"(i))

#if defined(__has_builtin)
#if __has_builtin(__builtin_amdgcn_mfma_f32_16x16x16f16)
#define HAVE_MFMA16 1
#endif
#if __has_builtin(__builtin_elementwise_fma)
#define HAS_EFMA 1
#endif
#endif
#ifndef HAVE_MFMA16
#define HAVE_MFMA16 0
#endif

typedef _Float16 half4v  __attribute__((ext_vector_type(4)));
typedef float    float4v __attribute__((ext_vector_type(4)));
typedef float    f32x2   __attribute__((ext_vector_type(2)));

struct Params {
    int      res[16];
    float    rm1[16];
    int      q_off[N_QUAD];
    unsigned magic[N_QUAD];
    int      shift[N_QUAD];
    int      p_off[N_PAIR];
};

__device__ __forceinline__ unsigned pack2(float a, float b) {
    return (unsigned)__half_as_ushort(__float2half(a))
         | ((unsigned)__half_as_ushort(__float2half(b)) << 16);
}
__device__ __forceinline__ float cvt_lo(unsigned u) {
    return __half2float(__ushort_as_half((unsigned short)(u & 0xffffu)));
}
__device__ __forceinline__ float cvt_hi(unsigned u) {
    return __half2float(__ushort_as_half((unsigned short)(u >> 16)));
}
__device__ __forceinline__ float bilerp(float A0, float A1, float B0, float B1,
                                        float w, float v) {
    f32x2 A = {A0, A1}, B = {B0, B1}, W = {w, w};
#if defined(HAS_EFMA)
    f32x2 R = __builtin_elementwise_fma(W, B - A, A);
#else
    f32x2 R = {fmaf(w, B0 - A0, A0), fmaf(w, B1 - A1, A1)};
#endif
    return fmaf(v, R.y - R.x, R.x);
}

__global__ __launch_bounds__(TPB, 4) void shacira_fwd(
    const float* __restrict__ x,
    const float* __restrict__ latents,
    const float* __restrict__ dec_w,
    const float* __restrict__ dec_b,
    const float* __restrict__ w1,
    const float* __restrict__ b1,
    const float* __restrict__ w2,
    const float* __restrict__ b2,
    float* __restrict__ out,
    Params pr)
{
    __shared__ __align__(16) unsigned char smem[SMEM_BYTES];
    unsigned short* hl = (unsigned short*)(smem + HL_OFF);
    uint2*          dq = (uint2*)(smem + DQ_OFF);
    unsigned*       dp = (unsigned*)(smem + DP_OFF);
#if HAVE_MFMA16
    unsigned*   bounce = (unsigned*)(smem + BN_OFF);
#endif

    const int tid = threadIdx.x;
    const float dw = dec_w[0];
    const float db = dec_b[0];

    // ---- stage quad LODs 0..3 ----
    #pragma unroll
    for (int l = 0; l < N_QUAD; ++l) {
        const int res = pr.res[l];
        const int n = res * res;
        const unsigned M = pr.magic[l];
        const int sh = pr.shift[l];
        const int off = pr.q_off[l];
        const float* lat = latents + l * CODEBOOK;
        for (int e = tid; e < n; e += TPB) {
            int ix = (int)(((unsigned)e * M) >> sh);
            int iy = e - ix * res;
            int ixp = min(ix + 1, res - 1);
            int iyp = min(iy + 1, res - 1);
            const float* r0 = lat + ix * res;
            const float* r1 = lat + ixp * res;
            uint2 qv;
            qv.x = pack2(fmaf(r0[iy],  dw, db), fmaf(r1[iy],  dw, db));
            qv.y = pack2(fmaf(r0[iyp], dw, db), fmaf(r1[iyp], dw, db));
            dq[off + e] = qv;
        }
    }
    // ---- stage pair LODs 4..6 ----
    #pragma unroll
    for (int l = 0; l < N_PAIR; ++l) {
        const int res = pr.res[4 + l];
        const int n = res * res;
        const int off = pr.p_off[l];
        const float* lat = latents + (4 + l) * CODEBOOK;
        for (int e = tid; e < n; e += TPB) {
            float a = fmaf(lat[e],     dw, db);
            float b = fmaf(lat[e + 1], dw, db);
            dp[off + e] = pack2(a, b);
        }
    }
    // ---- stage hashed LODs 7..15 as f16 bit patterns ----
    #pragma unroll
    for (int l = 0; l < N_HASH; ++l) {
        const float* lat = latents + (N_DENSE + l) * CODEBOOK;
        for (int e = tid; e < CODEBOOK; e += TPB)
            hl[l * CODEBOOK + e] = __half_as_ushort(__float2half(fmaf(lat[e], dw, db)));
    }
    __syncthreads();

    const int lane = tid & 63;
    const int wid  = tid >> 6;
    const int q    = lane >> 4;
    const int r15  = lane & 15;
    const char* hp  = (const char*)smem;
    const char* hp8 = (const char*)smem + 65536;

#if HAVE_MFMA16
    half4v a1f, a2f;
    float4v c1f, c2f;
    #pragma unroll
    for (int j = 0; j < 4; ++j) {
        const int k = q * 4 + j;
        a1f[j] = (_Float16)w1[k * 16 + r15];
        a2f[j] = (r15 < 3) ? (_Float16)w2[k * 3 + r15] : (_Float16)0.f;
        c1f[j] = b1[k];
        c2f[j] = b2[min(k, 2)];
    }
    const int sW = (lane >> 2) & 1;
    const int sR = (r15 >> 2) & 1;
    unsigned* wbase = &bounce[wid * 512 + lane * 8];
#endif

    const int pbase0 = blockIdx.x * PTS_PER_BLOCK;
    const float2* xp = reinterpret_cast<const float2*>(x) + pbase0;
    float* outp = out + (size_t)pbase0 * 3;

    float2 xy = xp[tid];

    for (int c = 0; c < CHUNKS; ++c) {
        const int t64 = c * TPB + (tid & ~63);

        float fxs[8], fys[8];
        uint2 qvv[N_QUAD];
        unsigned pu0[N_PAIR], pu1[N_PAIR];
        unsigned h7[4];
        unsigned hv[8][4];
        float h[16];

        // ====== Prologue: issue quads(4) + pairs(6) + h7(4) = 14 outstanding ======
        #pragma unroll
        for (int l = 0; l < 8; ++l) {
            const int res = pr.res[l];
            f32x2 pxy = (f32x2){xy.x, xy.y} * (f32x2){pr.rm1[l], pr.rm1[l]};
            int i0x = (int)pxy.x, i0y = (int)pxy.y;
            fxs[l] = __builtin_amdgcn_fractf(pxy.x);
            fys[l] = __builtin_amdgcn_fractf(pxy.y);
            if (l < N_QUAD) {
                qvv[l] = dq[pr.q_off[l] + (int)__umul24((unsigned)i0x, (unsigned)res) + i0y];
            } else if (l < N_DENSE) {
                int e = pr.p_off[l - 4] + (int)__umul24((unsigned)i0x, (unsigned)res) + i0y;
                pu0[l - 4] = dp[e];
                pu1[l - 4] = dp[e + res];
            } else {
                unsigned ux0b = (unsigned)(i0x << 1), ux1b = ux0b + 2u;
                unsigned hyb0 = __umul24((unsigned)i0y, PRIME_B2);
                unsigned hyb1 = hyb0 + PRIME_B2;
                h7[0] = (unsigned)*(const unsigned short*)(hp + ((ux0b ^ hyb0) & 0x1FFEu));
                h7[1] = (unsigned)*(const unsigned short*)(hp + ((ux1b ^ hyb0) & 0x1FFEu));
                h7[2] = (unsigned)*(const unsigned short*)(hp + ((ux0b ^ hyb1) & 0x1FFEu));
                h7[3] = (unsigned)*(const unsigned short*)(hp + ((ux1b ^ hyb1) & 0x1FFEu));
            }
        }
        PIN8(qvv[0].x, qvv[0].y, qvv[1].x, qvv[1].y, qvv[2].x, qvv[2].y, qvv[3].x, qvv[3].y);
        PIN8(pu0[0], pu0[1], pu0[2], pu1[0], pu1[1], pu1[2], h7[0], h7[1]);
        PIN2(h7[2], h7[3]);

        // prefetch next chunk's coords (vmem counter, independent)
        const int cn = (c + 1 < CHUNKS) ? (c + 1) : c;
        float2 xy_next = xp[cn * TPB + tid];

        // issue of hash LOD 8+i (4 ds_read_u16), pinned right after issue
        #define ISSUE_HV(i)                                                            \
        do {                                                                           \
            const int l = 8 + (i);                                                     \
            f32x2 pxy = (f32x2){xy.x, xy.y} * (f32x2){pr.rm1[l], pr.rm1[l]};           \
            int i0x = (int)pxy.x, i0y = (int)pxy.y;                                    \
            unsigned ux0b = (unsigned)(i0x << 1), ux1b = ux0b + 2u;                    \
            unsigned hyb0 = __umul24((unsigned)i0y, PRIME_B2);                         \
            unsigned hyb1 = hyb0 + PRIME_B2;                                           \
            const char* tb = ((i) < 7) ? (hp + 8192 * ((i) + 1)) : hp8;                \
            hv[i][0] = (unsigned)*(const unsigned short*)(tb + ((ux0b ^ hyb0) & 0x1FFEu)); \
            hv[i][1] = (unsigned)*(const unsigned short*)(tb + ((ux1b ^ hyb0) & 0x1FFEu)); \
            hv[i][2] = (unsigned)*(const unsigned short*)(tb + ((ux0b ^ hyb1) & 0x1FFEu)); \
            hv[i][3] = (unsigned)*(const unsigned short*)(tb + ((ux1b ^ hyb1) & 0x1FFEu)); \
            PIN4(hv[i][0], hv[i][1], hv[i][2], hv[i][3]);                              \
        } while (0)

        // math of hash LOD 8+i, result pinned right after (freezes position)
        #define MATH_HV(i)                                                             \
        do {                                                                           \
            const int l = 8 + (i);                                                     \
            f32x2 pxy = (f32x2){xy.x, xy.y} * (f32x2){pr.rm1[l], pr.rm1[l]};           \
            float fx = __builtin_amdgcn_fractf(pxy.x);                                 \
            float fy = __builtin_amdgcn_fractf(pxy.y);                                 \
            h[l] = bilerp(cvt_lo(hv[i][0]), cvt_lo(hv[i][1]),                          \
                          cvt_lo(hv[i][2]), cvt_lo(hv[i][3]), fy, fx);                 \
            PIN1(h[l]);                                                                \
        } while (0)

        // ====== Modulo schedule: alternate math_k / issue_{k+2}, <=14 in flight ======
        // math quads (their 4 loads are oldest -> partial lgkm wait)
        #pragma unroll
        for (int l = 0; l < N_QUAD; ++l)
            h[l] = bilerp(cvt_lo(qvv[l].x), cvt_lo(qvv[l].y),
                          cvt_hi(qvv[l].x), cvt_hi(qvv[l].y), fxs[l], fys[l]);
        PIN4(h[0], h[1], h[2], h[3]);

        ISSUE_HV(0);

        #pragma unroll
        for (int l = N_QUAD; l < N_DENSE; ++l)
            h[l] = bilerp(cvt_lo(pu0[l - 4]), cvt_lo(pu1[l - 4]),
                          cvt_hi(pu0[l - 4]), cvt_hi(pu1[l - 4]), fys[l], fxs[l]);
        PIN3(h[4], h[5], h[6]);

        ISSUE_HV(1);

        h[7] = bilerp(cvt_lo(h7[0]), cvt_lo(h7[1]), cvt_lo(h7[2]), cvt_lo(h7[3]),
                      fys[7], fxs[7]);
        PIN1(h[7]);

        ISSUE_HV(2);  MATH_HV(0);
        ISSUE_HV(3);  MATH_HV(1);
        ISSUE_HV(4);  MATH_HV(2);
        ISSUE_HV(5);  MATH_HV(3);
        ISSUE_HV(6);  MATH_HV(4);
        ISSUE_HV(7);  MATH_HV(5);
        MATH_HV(6);
        MATH_HV(7);

        #undef ISSUE_HV
        #undef MATH_HV

#if HAVE_MFMA16
        // ---- pack h to f16 and transpose via wave-private LDS bounce ----
        unsigned hw[8];
        #pragma unroll
        for (int i = 0; i < 8; ++i)
            hw[i] = __builtin_bit_cast(unsigned,
                        __builtin_amdgcn_cvt_pkrtz(h[2 * i], h[2 * i + 1]));
        *reinterpret_cast<uint4*>(wbase + sW * 4)       = uint4{hw[0], hw[1], hw[2], hw[3]};
        *reinterpret_cast<uint4*>(wbase + (sW ^ 1) * 4) = uint4{hw[4], hw[5], hw[6], hw[7]};

        #pragma unroll
        for (int t = 0; t < 4; ++t) {
            const int row = 16 * t + r15;
            const unsigned* rb = &bounce[wid * 512 + row * 8 + ((q * 2) ^ (sR * 4))];
            half4v bf = *reinterpret_cast<const half4v*>(rb);
            float4v d1 = __builtin_amdgcn_mfma_f32_16x16x16f16(a1f, bf, c1f, 0, 0, 0);
            unsigned u0 = __builtin_bit_cast(unsigned,
                              __builtin_amdgcn_cvt_pkrtz(fmaxf(d1[0], 0.f), fmaxf(d1[1], 0.f)));
            unsigned u1 = __builtin_bit_cast(unsigned,
                              __builtin_amdgcn_cvt_pkrtz(fmaxf(d1[2], 0.f), fmaxf(d1[3], 0.f)));
            uint2 uu; uu.x = u0; uu.y = u1;
            half4v rp = __builtin_bit_cast(half4v, uu);
            float4v d2 = __builtin_amdgcn_mfma_f32_16x16x16f16(a2f, rp, c2f, 0, 0, 0);
            if (lane < 16) {
                float* op = outp + (size_t)(t64 + 16 * t + r15) * 3;
                op[0] = d2[0]; op[1] = d2[1]; op[2] = d2[2];
            }
        }
#else
        float o0 = b2[0], o1 = b2[1], o2 = b2[2];
        #pragma unroll
        for (int k = 0; k < 16; ++k) {
            float acc = b1[k];
            #pragma unroll
            for (int l = 0; l < 16; ++l)
                acc = fmaf(h[l], w1[l * 16 + k], acc);
            acc = fmaxf(acc, 0.f);
            o0 = fmaf(acc, w2[k * 3 + 0], o0);
            o1 = fmaf(acc, w2[k * 3 + 1], o1);
            o2 = fmaf(acc, w2[k * 3 + 2], o2);
        }
        float* op = outp + (size_t)(t64 + lane) * 3;
        op[0] = o0; op[1] = o1; op[2] = o2;
#endif
        xy = xy_next;
    }
}

extern "C" void kernel_launch(void* const* d_in, const int* in_sizes, int n_in,
                              void* d_out, int out_size, void* d_ws, size_t ws_size,
                              hipStream_t stream)
{
    Params pr;
    const double growth = pow(512.0 / 16.0, 1.0 / 15.0);
    for (int l = 0; l < 16; ++l) {
        pr.res[l] = (int)floor(16.0 * pow(growth, (double)l));
        pr.rm1[l] = (float)(pr.res[l] - 1);
    }
    int qoff = 0;
    for (int l = 0; l < N_QUAD; ++l) {
        pr.q_off[l] = qoff;
        qoff += pr.res[l] * pr.res[l];
        const int d = pr.res[l];
        pr.magic[l] = 0; pr.shift[l] = 0;
        for (int s = 12; s <= 23; ++s) {
            unsigned long long M = ((1ull << s) + d - 1) / d;
            if ((unsigned long long)(d * d - 1) * M >= (1ull << 32)) continue;
            bool ok = true;
            for (int e = 0; e < d * d; ++e)
                if ((int)(((unsigned long long)e * M) >> s) != e / d) { ok = false; break; }
            if (ok) { pr.magic[l] = (unsigned)M; pr.shift[l] = s; break; }
        }
    }
    int poff = 0;
    for (int l = 0; l < N_PAIR; ++l) {
        pr.p_off[l] = poff;
        poff += pr.res[4 + l] * pr.res[4 + l];
    }

    const int n = in_sizes[0] / 2;
    const int blocks = n / PTS_PER_BLOCK;

    shacira_fwd<<<blocks, TPB, 0, stream>>>(
        (const float*)d_in[0], (const float*)d_in[1], (const float*)d_in[2],
        (const float*)d_in[3], (const float*)d_in[4], (const float*)d_in[5],
        (const float*)d_in[6], (const float*)d_in[7], (float*)d_out, pr);
}